// Round 5
// baseline (93.082 us; speedup 1.0000x reference)
//
#include <hip/hip_runtime.h>

#define B_SZ 4096
#define D_SZ 1024
#define NB 32
#define DF 64          // features per eval tile
#define RB 64          // rows per eval tile
#define LSQ_STRIDE 9   // shifted-edge quads: 9 float4/feature (float stride 36 -> group (fl+o)%8)
#define CO_STRIDE  33  // coef quads: 33 float4/feature (float stride 132 -> group (fl+pos)%8)

constexpr float MBW = 0.001f;
constexpr float MBH = 0.001f;

// ---------------------------------------------------------------------------
// Kernel A: per-feature spline parameters. 256 thr = 8 features x 32 bins.
// Emits gCoef[f*32+k] = (a, b, c=d_left, d=chl) and shifted edge quads
// gLsQ[f*8+o] = (L[4o-1], L[4o], L[4o+1], L[4o+2]) with L[-1]=0, sentinel 2.0.
// Quad o serves bins 4o..4o+3: cnt = #(x>=y,z,w), cwl = quad[cnt].
// Also zeroes the logabsdet accumulators.
// ---------------------------------------------------------------------------
__global__ __launch_bounds__(256) void spline_params(
    const float* __restrict__ uw, const float* __restrict__ uh,
    const float* __restrict__ udl, const float* __restrict__ udr,
    float4* __restrict__ gCoef, float4* __restrict__ gLsQ,
    float* __restrict__ lad_out)
{
    const int tid = threadIdx.x;
    const int gidx = blockIdx.x * 256 + tid;
    if (gidx < B_SZ) lad_out[gidx] = 0.0f;

    const int f = blockIdx.x * 8 + (tid >> 5);
    const int k = tid & 31;

    const float w_raw = uw[f * NB + k];
    const float h_raw = uh[f * NB + k];

    float m = w_raw;
    for (int mm = 16; mm >= 1; mm >>= 1) m = fmaxf(m, __shfl_xor(m, mm));
    const float e = __expf(w_raw - m);
    float sum = e;
    for (int mm = 16; mm >= 1; mm >>= 1) sum += __shfl_xor(sum, mm);
    const float w = MBW + (1.0f - MBW * NB) * (e / sum);

    float mh = h_raw;
    for (int mm = 16; mm >= 1; mm >>= 1) mh = fmaxf(mh, __shfl_xor(mh, mm));
    const float eh = __expf(h_raw - mh);
    float sumh = eh;
    for (int mm = 16; mm >= 1; mm >>= 1) sumh += __shfl_xor(sumh, mm);
    const float h = MBH + (1.0f - MBH * NB) * (eh / sumh);

    const float slope = h / w;

    float cw = w, ch = h;
    for (int off = 1; off < 32; off <<= 1) {
        float t1 = __shfl_up(cw, off, 32);
        float t2 = __shfl_up(ch, off, 32);
        if (k >= off) { cw += t1; ch += t2; }
    }
    float chl = __shfl_up(ch, 1, 32); if (k == 0) chl = 0.0f;
    const float Ls = (k == 31) ? 2.0f : cw;

    const float slope_n = __shfl_down(slope, 1, 32);
    const float w_n     = __shfl_down(w, 1, 32);
    const float min1 = fminf(fabsf(slope), fabsf(slope_n));
    const float min2 = 0.5f * (w_n * slope + w * slope_n) / (w + w_n);
    const float sg  = (slope   > 0.f ? 1.f : 0.f) - (slope   < 0.f ? 1.f : 0.f);
    const float sgn = (slope_n > 0.f ? 1.f : 0.f) - (slope_n < 0.f ? 1.f : 0.f);
    const float inner = fminf(min1, min2) * (sg + sgn);

    float d_right;
    if (k == 31) {
        const float x = udr[f];
        d_right = (1.0f / (1.0f + __expf(-x))) * 3.0f * slope;
    } else {
        d_right = inner;
    }
    const float inner_prev = __shfl_up(inner, 1, 32);
    float d_left;
    if (k == 0) {
        const float x = udl[f];
        d_left = (1.0f / (1.0f + __expf(-x))) * 3.0f * slope;
    } else {
        d_left = inner_prev;
    }

    const float a = (d_left + d_right - 2.0f * slope) / (w * w);
    const float b = (3.0f * slope - 2.0f * d_left - d_right) / w;

    gCoef[f * NB + k] = make_float4(a, b, d_left, chl);

    float q0 = __shfl(Ls, (4 * k - 1) & 31, 32);
    float q1 = __shfl(Ls, (4 * k    ) & 31, 32);
    float q2 = __shfl(Ls, (4 * k + 1) & 31, 32);
    float q3 = __shfl(Ls, (4 * k + 2) & 31, 32);
    if (k == 0) q0 = 0.0f;                    // L[-1]
    if (k < 8) gLsQ[f * 8 + k] = make_float4(q0, q1, q2, q3);
}

// ---------------------------------------------------------------------------
// Kernel B: evaluate 64 feat x 64 rows per block, 512 thr (8 waves),
// grid = 1024 blocks (>=3 resident/CU at 42 KB LDS -> 24 waves/CU).
// Lane owns TWO consecutive features (float2 I/O, 512 B/wave): 14 coarse-edge
// regs instead of 28 -> low VGPR -> high occupancy (the R2->R4 lesson: cap
// via structure, not __launch_bounds__ min-waves which spills).
// Search: 7 register cmps (quad idx) -> ds_read_b128 shifted quad (cnt+cwl)
// -> ds_read_b128 coef. One __logf per lane-product of 2 derivatives.
// ---------------------------------------------------------------------------
__global__ __launch_bounds__(512) void spline_eval(
    const float2* __restrict__ inp,
    const float4* __restrict__ gCoef,
    const float4* __restrict__ gLsQ,
    float2* __restrict__ out, float* __restrict__ lad)
{
    __shared__ float4 sLsQ  [DF * LSQ_STRIDE];   //  9.2 KB
    __shared__ float4 sCoefQ[DF * CO_STRIDE];    // 33.8 KB (total 42 KB)

    const int tid = threadIdx.x;
    const int ft = blockIdx.x & (D_SZ / DF - 1);   // 16 feature tiles
    const int rt = blockIdx.x >> 4;                // 64 row tiles
    const int f0 = ft * DF;
    const int r0 = rt * RB;

    {
        const int fl = tid >> 3, o = tid & 7;
        sLsQ[fl * LSQ_STRIDE + o] = gLsQ[(f0 + fl) * 8 + o];
    }
    for (int t = tid; t < DF * NB; t += 512) {
        const int fl = t >> 5, kk = t & 31;
        sCoefQ[fl * CO_STRIDE + kk] = gCoef[(f0 + fl) * NB + kk];
    }
    __syncthreads();

    const int lane   = tid & 63;
    const int waveId = tid >> 6;        // 0..7
    const int sub    = lane >> 5;       // row within wave-iter: 0..1
    const int g      = lane & 31;       // 32-lane row-group position
    const int flbase = g * 2;

    // coarse quad boundaries -> registers: C[c] = L[4c+3] = quad(c+1).x
    float C0[7], C1[7];
    #pragma unroll
    for (int c = 0; c < 7; ++c) {
        C0[c] = sLsQ[(flbase + 0) * LSQ_STRIDE + c + 1].x;
        C1[c] = sLsQ[(flbase + 1) * LSQ_STRIDE + c + 1].x;
    }

    const int rbase = r0 + waveId * 2 + sub;
    const int base = ((rbase * D_SZ + f0) >> 1) + g;   // float2 index
    const int iterStride = 16 * D_SZ / 2;              // 16 rows per iter

    #pragma unroll 2
    for (int it = 0; it < RB / 16; ++it) {
        const float2 x2 = inp[base + it * iterStride];
        const float xv[2] = {x2.x, x2.y};

        float2 o2;
        float* ov = (float*)&o2;
        float prod = 1.0f;

        #pragma unroll
        for (int j = 0; j < 2; ++j) {
            const float x = xv[j];
            const float* Cp = (j == 0) ? C0 : C1;

            int o = 0;
            #pragma unroll
            for (int c = 0; c < 7; ++c) o += (x >= Cp[c]) ? 1 : 0;

            const float4 q = sLsQ[(flbase + j) * LSQ_STRIDE + o];
            const int cnt = (x >= q.y ? 1 : 0) + (x >= q.z ? 1 : 0)
                          + (x >= q.w ? 1 : 0);
            const float cwl = (cnt == 0) ? q.x
                            : (cnt == 1) ? q.y
                            : (cnt == 2) ? q.z : q.w;

            const float4 cf = sCoefQ[(flbase + j) * CO_STRIDE + 4 * o + cnt];
            const float s = x - cwl;
            float oo = ((cf.x * s + cf.y) * s + cf.z) * s + cf.w;
            ov[j] = fminf(fmaxf(oo, 0.0f), 1.0f);
            const float der = (3.0f * cf.x * s + 2.0f * cf.y) * s + cf.z;
            prod *= der;
        }

        out[base + it * iterStride] = o2;

        float lsum = __logf(fabsf(prod));
        #pragma unroll
        for (int mm = 16; mm >= 1; mm >>= 1) lsum += __shfl_xor(lsum, mm, 32);
        if (g == 0) atomicAdd(&lad[rbase + it * 16], lsum);
    }
}

// ---------------------------------------------------------------------------
extern "C" void kernel_launch(void* const* d_in, const int* in_sizes, int n_in,
                              void* d_out, int out_size, void* d_ws, size_t ws_size,
                              hipStream_t stream)
{
    const float* inputs = (const float*)d_in[0];
    const float* uw     = (const float*)d_in[1];
    const float* uh     = (const float*)d_in[2];
    const float* udl    = (const float*)d_in[3];
    const float* udr    = (const float*)d_in[4];

    float* out = (float*)d_out;                 // B*D outputs
    float* lad = out + (size_t)B_SZ * D_SZ;     // B logabsdet sums

    float4* gCoef = (float4*)d_ws;                                               // D*32*16B
    float4* gLsQ  = (float4*)((char*)d_ws + (size_t)D_SZ * NB * sizeof(float4)); // D*8*16B

    spline_params<<<D_SZ / 8, 256, 0, stream>>>(uw, uh, udl, udr, gCoef, gLsQ, lad);
    spline_eval<<<(D_SZ / DF) * (B_SZ / RB), 512, 0, stream>>>(
        (const float2*)inputs, gCoef, gLsQ, (float2*)out, lad);
}

// Round 6
// 87.506 us; speedup vs baseline: 1.0637x; 1.0637x over previous
//
#include <hip/hip_runtime.h>

#define B_SZ 4096
#define D_SZ 1024
#define NB 32
#define DF 64          // features per eval tile
#define RB 128         // rows per eval tile
#define LSQ_STRIDE 9   // shifted-edge quads: 9 float4 per feature
#define CO_STRIDE  33  // coef quads: 33 float4 per feature

constexpr float MBW = 0.001f;
constexpr float MBH = 0.001f;

// ---------------------------------------------------------------------------
// Kernel A: per-feature spline parameters. 256 thr = 8 features x 32 bins.
// Emits gCoef[f*32+k] = (a, b, c=d_left, d=chl) and shifted edge quads
// gLsQ[f*8+o] = (L[4o-1], L[4o], L[4o+1], L[4o+2]) with L[-1]=0, sentinel 2.0.
// Quad o serves bins 4o..4o+3: cnt = #(x>=y,z,w), cwl = quad[cnt].
// Also zeroes the logabsdet accumulators.
// ---------------------------------------------------------------------------
__global__ __launch_bounds__(256) void spline_params(
    const float* __restrict__ uw, const float* __restrict__ uh,
    const float* __restrict__ udl, const float* __restrict__ udr,
    float4* __restrict__ gCoef, float4* __restrict__ gLsQ,
    float* __restrict__ lad_out)
{
    const int tid = threadIdx.x;
    const int gidx = blockIdx.x * 256 + tid;
    if (gidx < B_SZ) lad_out[gidx] = 0.0f;

    const int f = blockIdx.x * 8 + (tid >> 5);
    const int k = tid & 31;

    const float w_raw = uw[f * NB + k];
    const float h_raw = uh[f * NB + k];

    float m = w_raw;
    for (int mm = 16; mm >= 1; mm >>= 1) m = fmaxf(m, __shfl_xor(m, mm));
    const float e = __expf(w_raw - m);
    float sum = e;
    for (int mm = 16; mm >= 1; mm >>= 1) sum += __shfl_xor(sum, mm);
    const float w = MBW + (1.0f - MBW * NB) * (e / sum);

    float mh = h_raw;
    for (int mm = 16; mm >= 1; mm >>= 1) mh = fmaxf(mh, __shfl_xor(mh, mm));
    const float eh = __expf(h_raw - mh);
    float sumh = eh;
    for (int mm = 16; mm >= 1; mm >>= 1) sumh += __shfl_xor(sumh, mm);
    const float h = MBH + (1.0f - MBH * NB) * (eh / sumh);

    const float slope = h / w;

    float cw = w, ch = h;
    for (int off = 1; off < 32; off <<= 1) {
        float t1 = __shfl_up(cw, off, 32);
        float t2 = __shfl_up(ch, off, 32);
        if (k >= off) { cw += t1; ch += t2; }
    }
    float chl = __shfl_up(ch, 1, 32); if (k == 0) chl = 0.0f;
    const float Ls = (k == 31) ? 2.0f : cw;

    const float slope_n = __shfl_down(slope, 1, 32);
    const float w_n     = __shfl_down(w, 1, 32);
    const float min1 = fminf(fabsf(slope), fabsf(slope_n));
    const float min2 = 0.5f * (w_n * slope + w * slope_n) / (w + w_n);
    const float sg  = (slope   > 0.f ? 1.f : 0.f) - (slope   < 0.f ? 1.f : 0.f);
    const float sgn = (slope_n > 0.f ? 1.f : 0.f) - (slope_n < 0.f ? 1.f : 0.f);
    const float inner = fminf(min1, min2) * (sg + sgn);

    float d_right;
    if (k == 31) {
        const float x = udr[f];
        d_right = (1.0f / (1.0f + __expf(-x))) * 3.0f * slope;
    } else {
        d_right = inner;
    }
    const float inner_prev = __shfl_up(inner, 1, 32);
    float d_left;
    if (k == 0) {
        const float x = udl[f];
        d_left = (1.0f / (1.0f + __expf(-x))) * 3.0f * slope;
    } else {
        d_left = inner_prev;
    }

    const float a = (d_left + d_right - 2.0f * slope) / (w * w);
    const float b = (3.0f * slope - 2.0f * d_left - d_right) / w;

    gCoef[f * NB + k] = make_float4(a, b, d_left, chl);

    float q0 = __shfl(Ls, (4 * k - 1) & 31, 32);
    float q1 = __shfl(Ls, (4 * k    ) & 31, 32);
    float q2 = __shfl(Ls, (4 * k + 1) & 31, 32);
    float q3 = __shfl(Ls, (4 * k + 2) & 31, 32);
    if (k == 0) q0 = 0.0f;                    // L[-1]
    if (k < 8) gLsQ[f * 8 + k] = make_float4(q0, q1, q2, q3);
}

// ---------------------------------------------------------------------------
// Kernel B: evaluate 64 feat x 128 rows per block, 512 thr (8 waves),
// grid 512. Lane owns FOUR consecutive features (float4 I/O, 1 KB/wave);
// 16 lanes cover a row; wave covers 4 rows/iter, 4 fully-unrolled iters
// (4 independent load chains for the scheduler — no explicit prefetch, no
// __launch_bounds__ min-waves: R4 showed the cap forces spills at ~110 VGPR
// natural demand).
// Search: 7 register cmps (quad idx o) -> 1 ds_read_b128 shifted quad
// (cnt + cwl directly) -> 1 ds_read_b128 coef. One __logf per 4 elements.
// ---------------------------------------------------------------------------
__global__ __launch_bounds__(512) void spline_eval(
    const float4* __restrict__ inp,
    const float4* __restrict__ gCoef,
    const float4* __restrict__ gLsQ,
    float4* __restrict__ out, float* __restrict__ lad)
{
    __shared__ float4 sLsQ  [DF * LSQ_STRIDE];   //  9.2 KB
    __shared__ float4 sCoefQ[DF * CO_STRIDE];    // 33.8 KB (total 42 KB)

    const int tid = threadIdx.x;
    const int ft = blockIdx.x & (D_SZ / DF - 1);   // 16 feature tiles
    const int rt = blockIdx.x >> 4;                // 32 row tiles
    const int f0 = ft * DF;
    const int r0 = rt * RB;

    {
        const int fl = tid >> 3, o = tid & 7;
        sLsQ[fl * LSQ_STRIDE + o] = gLsQ[(f0 + fl) * 8 + o];
    }
    for (int t = tid; t < DF * NB; t += 512) {
        const int fl = t >> 5, kk = t & 31;
        sCoefQ[fl * CO_STRIDE + kk] = gCoef[(f0 + fl) * NB + kk];
    }
    __syncthreads();

    const int lane   = tid & 63;
    const int waveId = tid >> 6;        // 0..7
    const int sub    = lane >> 4;       // row within wave-iter: 0..3
    const int g      = lane & 15;       // 16-lane row-group position
    const int flbase = g * 4;

    // coarse quad boundaries -> registers: C[c] = L[4c+3] = quad(c+1).x
    float C0[7], C1[7], C2[7], C3[7];
    #pragma unroll
    for (int c = 0; c < 7; ++c) {
        C0[c] = sLsQ[(flbase + 0) * LSQ_STRIDE + c + 1].x;
        C1[c] = sLsQ[(flbase + 1) * LSQ_STRIDE + c + 1].x;
        C2[c] = sLsQ[(flbase + 2) * LSQ_STRIDE + c + 1].x;
        C3[c] = sLsQ[(flbase + 3) * LSQ_STRIDE + c + 1].x;
    }

    const int rbase = r0 + waveId * 4 + sub;
    const int base = ((rbase * D_SZ + f0) >> 2) + g;  // float4 index
    const int iterStride = 32 * D_SZ / 4;             // 32 rows per iter

    #pragma unroll
    for (int it = 0; it < RB / 32; ++it) {
        const float4 x4 = inp[base + it * iterStride];
        const float xv[4] = {x4.x, x4.y, x4.z, x4.w};

        float4 o4;
        float* ov = (float*)&o4;
        float prod = 1.0f;

        #pragma unroll
        for (int j = 0; j < 4; ++j) {
            const float x = xv[j];
            const float* Cp = (j == 0) ? C0 : (j == 1) ? C1 : (j == 2) ? C2 : C3;

            int o = 0;
            #pragma unroll
            for (int c = 0; c < 7; ++c) o += (x >= Cp[c]) ? 1 : 0;

            const float4 q = sLsQ[(flbase + j) * LSQ_STRIDE + o];
            const int cnt = (x >= q.y ? 1 : 0) + (x >= q.z ? 1 : 0)
                          + (x >= q.w ? 1 : 0);
            const float cwl = (cnt == 0) ? q.x
                            : (cnt == 1) ? q.y
                            : (cnt == 2) ? q.z : q.w;

            const float4 cf = sCoefQ[(flbase + j) * CO_STRIDE + 4 * o + cnt];
            const float s = x - cwl;
            float oo = ((cf.x * s + cf.y) * s + cf.z) * s + cf.w;
            ov[j] = fminf(fmaxf(oo, 0.0f), 1.0f);
            const float der = (3.0f * cf.x * s + 2.0f * cf.y) * s + cf.z;
            prod *= der;
        }

        out[base + it * iterStride] = o4;

        float lsum = __logf(fabsf(prod));
        #pragma unroll
        for (int mm = 8; mm >= 1; mm >>= 1) lsum += __shfl_xor(lsum, mm, 16);
        if (g == 0) atomicAdd(&lad[rbase + it * 32], lsum);
    }
}

// ---------------------------------------------------------------------------
extern "C" void kernel_launch(void* const* d_in, const int* in_sizes, int n_in,
                              void* d_out, int out_size, void* d_ws, size_t ws_size,
                              hipStream_t stream)
{
    const float* inputs = (const float*)d_in[0];
    const float* uw     = (const float*)d_in[1];
    const float* uh     = (const float*)d_in[2];
    const float* udl    = (const float*)d_in[3];
    const float* udr    = (const float*)d_in[4];

    float* out = (float*)d_out;                 // B*D outputs
    float* lad = out + (size_t)B_SZ * D_SZ;     // B logabsdet sums

    float4* gCoef = (float4*)d_ws;                                               // D*32*16B
    float4* gLsQ  = (float4*)((char*)d_ws + (size_t)D_SZ * NB * sizeof(float4)); // D*8*16B

    spline_params<<<D_SZ / 8, 256, 0, stream>>>(uw, uh, udl, udr, gCoef, gLsQ, lad);
    spline_eval<<<(D_SZ / DF) * (B_SZ / RB), 512, 0, stream>>>(
        (const float4*)inputs, gCoef, gLsQ, (float4*)out, lad);
}

// Round 7
// 83.936 us; speedup vs baseline: 1.1090x; 1.0425x over previous
//
#include <hip/hip_runtime.h>

#define B_SZ 4096
#define D_SZ 1024
#define NB 32
#define DF 16          // features per tile
#define RB 512         // rows per tile
#define LSQ_STRIDE 9   // shifted-edge quads: 9 float4 per feature
#define CO_STRIDE  33  // coef quads: 33 float4 per feature

constexpr float MBW = 0.001f;
constexpr float MBH = 0.001f;

// ---------------------------------------------------------------------------
// Single fused kernel. Block = 512 thr (8 waves), tile = 16 feat x 512 rows,
// grid = 64 f-tiles x 8 r-tiles = 512 blocks (2/CU).
//
// Phase 1 (one pass, 8x total redundancy): 16 segments of 32 lanes each run
// the softmax/cumsum/monotone-derivative pipeline for one feature, writing
// coef quads (a,b,c=d_left,d=chl) and shifted edge quads
// (L[4o-1],L[4o],L[4o+1],L[4o+2]) into 10.8 KB of LDS. No global round-trip,
// no second launch, no inter-kernel drain.
//
// Phase 2: lane owns 4 consecutive features (quad = lane>>4), row = lane&15;
// float4 I/O (full 64B lines, 1 KB/wave). Search: 7 register cmps (quad idx)
// -> 1 ds_read_b128 shifted quad (cnt + cwl) -> 1 ds_read_b128 coef.
// One __logf per lane (product of 4 ders); 2 shfl_xor + 16-lane atomic
// finish the 16-feature row partial.
// ---------------------------------------------------------------------------
__global__ __launch_bounds__(512) void spline_fused(
    const float* __restrict__ uw, const float* __restrict__ uh,
    const float* __restrict__ udl, const float* __restrict__ udr,
    const float4* __restrict__ inp,
    float4* __restrict__ out, float* __restrict__ lad)
{
    __shared__ float4 sLsQ  [DF * LSQ_STRIDE];   // 2.3 KB
    __shared__ float4 sCoefQ[DF * CO_STRIDE];    // 8.45 KB

    const int tid = threadIdx.x;
    const int ft = blockIdx.x & 63;              // 64 feature tiles
    const int rt = blockIdx.x >> 6;              // 8 row tiles
    const int f0 = ft * DF;
    const int r0 = rt * RB;

    // ---------------- phase 1: params, one segment per feature ----------------
    {
        const int s = tid >> 5;        // feature within tile: 0..15
        const int k = tid & 31;        // bin
        const int f = f0 + s;

        const float w_raw = uw[f * NB + k];
        const float h_raw = uh[f * NB + k];

        float m = w_raw;
        for (int mm = 16; mm >= 1; mm >>= 1) m = fmaxf(m, __shfl_xor(m, mm));
        const float e = __expf(w_raw - m);
        float sum = e;
        for (int mm = 16; mm >= 1; mm >>= 1) sum += __shfl_xor(sum, mm);
        const float w = MBW + (1.0f - MBW * NB) * (e / sum);

        float mh = h_raw;
        for (int mm = 16; mm >= 1; mm >>= 1) mh = fmaxf(mh, __shfl_xor(mh, mm));
        const float eh = __expf(h_raw - mh);
        float sumh = eh;
        for (int mm = 16; mm >= 1; mm >>= 1) sumh += __shfl_xor(sumh, mm);
        const float h = MBH + (1.0f - MBH * NB) * (eh / sumh);

        const float slope = h / w;

        float cw = w, ch = h;
        for (int off = 1; off < 32; off <<= 1) {
            float t1 = __shfl_up(cw, off, 32);
            float t2 = __shfl_up(ch, off, 32);
            if (k >= off) { cw += t1; ch += t2; }
        }
        float chl = __shfl_up(ch, 1, 32); if (k == 0) chl = 0.0f;
        const float Ls = (k == 31) ? 2.0f : cw;   // sentinel > any x in [0,1)

        const float slope_n = __shfl_down(slope, 1, 32);
        const float w_n     = __shfl_down(w, 1, 32);
        const float min1 = fminf(fabsf(slope), fabsf(slope_n));
        const float min2 = 0.5f * (w_n * slope + w * slope_n) / (w + w_n);
        const float sg  = (slope   > 0.f ? 1.f : 0.f) - (slope   < 0.f ? 1.f : 0.f);
        const float sgn = (slope_n > 0.f ? 1.f : 0.f) - (slope_n < 0.f ? 1.f : 0.f);
        const float inner = fminf(min1, min2) * (sg + sgn);

        float d_right;
        if (k == 31) {
            const float x = udr[f];
            d_right = (1.0f / (1.0f + __expf(-x))) * 3.0f * slope;
        } else {
            d_right = inner;
        }
        const float inner_prev = __shfl_up(inner, 1, 32);
        float d_left;
        if (k == 0) {
            const float x = udl[f];
            d_left = (1.0f / (1.0f + __expf(-x))) * 3.0f * slope;
        } else {
            d_left = inner_prev;
        }

        const float a = (d_left + d_right - 2.0f * slope) / (w * w);
        const float b = (3.0f * slope - 2.0f * d_left - d_right) / w;

        sCoefQ[s * CO_STRIDE + k] = make_float4(a, b, d_left, chl);

        float q0 = __shfl(Ls, (4 * k - 1) & 31, 32);
        float q1 = __shfl(Ls, (4 * k    ) & 31, 32);
        float q2 = __shfl(Ls, (4 * k + 1) & 31, 32);
        float q3 = __shfl(Ls, (4 * k + 2) & 31, 32);
        if (k == 0) q0 = 0.0f;                    // L[-1]
        if (k < 8) sLsQ[s * LSQ_STRIDE + k] = make_float4(q0, q1, q2, q3);
    }
    __syncthreads();

    // ---------------- phase 2: evaluate ----------------
    const int lane   = tid & 63;
    const int waveId = tid >> 6;          // 0..7
    const int flq    = lane >> 4;         // feature quad: 0..3
    const int rl     = lane & 15;         // row within wave group
    const int flbase = flq * 4;

    // coarse quad boundaries -> registers: C[c] = L[4c+3] = quad(c+1).x
    float C0[7], C1[7], C2[7], C3[7];
    #pragma unroll
    for (int c = 0; c < 7; ++c) {
        C0[c] = sLsQ[(flbase + 0) * LSQ_STRIDE + c + 1].x;
        C1[c] = sLsQ[(flbase + 1) * LSQ_STRIDE + c + 1].x;
        C2[c] = sLsQ[(flbase + 2) * LSQ_STRIDE + c + 1].x;
        C3[c] = sLsQ[(flbase + 3) * LSQ_STRIDE + c + 1].x;
    }

    const int rbase = r0 + waveId * 16 + rl;          // +128 per iter
    const int base  = rbase * (D_SZ / 4) + ft * 4 + flq;
    const int iterStride = 128 * (D_SZ / 4);          // 128 rows per iter

    #pragma unroll
    for (int it = 0; it < RB / 128; ++it) {
        const float4 x4 = inp[base + it * iterStride];
        const float xv[4] = {x4.x, x4.y, x4.z, x4.w};

        float4 o4;
        float* ov = (float*)&o4;
        float prod = 1.0f;

        #pragma unroll
        for (int j = 0; j < 4; ++j) {
            const float x = xv[j];
            const float* Cp = (j == 0) ? C0 : (j == 1) ? C1 : (j == 2) ? C2 : C3;

            int o = 0;
            #pragma unroll
            for (int c = 0; c < 7; ++c) o += (x >= Cp[c]) ? 1 : 0;

            const float4 q = sLsQ[(flbase + j) * LSQ_STRIDE + o];
            const int cnt = (x >= q.y ? 1 : 0) + (x >= q.z ? 1 : 0)
                          + (x >= q.w ? 1 : 0);
            const float cwl = (cnt == 0) ? q.x
                            : (cnt == 1) ? q.y
                            : (cnt == 2) ? q.z : q.w;

            const float4 cf = sCoefQ[(flbase + j) * CO_STRIDE + 4 * o + cnt];
            const float s = x - cwl;
            float oo = ((cf.x * s + cf.y) * s + cf.z) * s + cf.w;
            ov[j] = fminf(fmaxf(oo, 0.0f), 1.0f);
            const float der = (3.0f * cf.x * s + 2.0f * cf.y) * s + cf.z;
            prod *= der;
        }

        out[base + it * iterStride] = o4;

        // sum across the 4 feature quads (xor classes share lane&15 == row)
        float lsum = __logf(fabsf(prod));
        lsum += __shfl_xor(lsum, 16);
        lsum += __shfl_xor(lsum, 32);
        if (lane < 16) atomicAdd(&lad[rbase + it * 128], lsum);
    }
}

// ---------------------------------------------------------------------------
extern "C" void kernel_launch(void* const* d_in, const int* in_sizes, int n_in,
                              void* d_out, int out_size, void* d_ws, size_t ws_size,
                              hipStream_t stream)
{
    const float* inputs = (const float*)d_in[0];
    const float* uw     = (const float*)d_in[1];
    const float* uh     = (const float*)d_in[2];
    const float* udl    = (const float*)d_in[3];
    const float* udr    = (const float*)d_in[4];

    float* out = (float*)d_out;                 // B*D outputs
    float* lad = out + (size_t)B_SZ * D_SZ;     // B logabsdet sums

    hipMemsetAsync(lad, 0, (size_t)B_SZ * sizeof(float), stream);
    spline_fused<<<(D_SZ / DF) * (B_SZ / RB), 512, 0, stream>>>(
        uw, uh, udl, udr, (const float4*)inputs, (float4*)out, lad);
}